// Round 13
// baseline (45.355 us; speedup 1.0000x reference)
//
#include <hip/hip_runtime.h>

#define NQ 12
#define TPB 128   // 2 waves per block; ONE batch element per wave

// Wave-per-element, barrier-free design. Each wave owns a private 32KB LDS
// region holding its element's 4096 complex amps; each lane holds 64 amps
// (128 VGPRs). A layer = 2 register passes (state bits 11..6, then 5..0)
// with an LDS exchange between them. No __syncthreads anywhere: all LDS
// dependencies are intra-wave (DS ops are in-order per wave, and every
// stored value data-depends on all 64 loads through the butterfly network).
// Canonical layout: phys = swz(i) = i ^ ((i>>6)&63).
// Layer 1 folded into init (product state, Gray perm absorbed via j=g(i)).
// Per-layer CNOT Gray perm new[j]=old[g(j)] applied as g^-1 scatter at the
// pass-2 store. Layer 6 amputated to gate 60 only (commutes out of <Z_0>).

__device__ __forceinline__ float RL(float v, int idx) {
    return __int_as_float(__builtin_amdgcn_readlane(__float_as_int(v), idx));
}
__device__ __forceinline__ float2 cmul(float2 u, float2 v) {
    return make_float2(fmaf(u.x, v.x, -u.y * v.y),
                       fmaf(u.x, v.y,  u.y * v.x));
}
// Rot(phi,theta,omega): u00=(A,-B) u01=(-C,-D) u10=(C,-D) u11=(A,B)
__device__ __forceinline__ void bf1(float2& s0, float2& s1,
                                    float A, float B, float C, float D) {
    float n0x = fmaf(A, s0.x, fmaf( B, s0.y, fmaf(-C, s1.x,  D * s1.y)));
    float n0y = fmaf(A, s0.y, fmaf(-B, s0.x, fmaf(-C, s1.y, -D * s1.x)));
    float n1x = fmaf(C, s0.x, fmaf( D, s0.y, fmaf( A, s1.x, -B * s1.y)));
    float n1y = fmaf(C, s0.y, fmaf(-D, s0.x, fmaf( A, s1.y,  B * s1.x)));
    s0 = make_float2(n0x, n0y); s1 = make_float2(n1x, n1y);
}

#define BF(i,j) bf1(a##i, a##j, A, B, C, D);
#define PL1  BF(0,1)BF(2,3)BF(4,5)BF(6,7)BF(8,9)BF(10,11)BF(12,13)BF(14,15)\
             BF(16,17)BF(18,19)BF(20,21)BF(22,23)BF(24,25)BF(26,27)BF(28,29)BF(30,31)\
             BF(32,33)BF(34,35)BF(36,37)BF(38,39)BF(40,41)BF(42,43)BF(44,45)BF(46,47)\
             BF(48,49)BF(50,51)BF(52,53)BF(54,55)BF(56,57)BF(58,59)BF(60,61)BF(62,63)
#define PL2  BF(0,2)BF(1,3)BF(4,6)BF(5,7)BF(8,10)BF(9,11)BF(12,14)BF(13,15)\
             BF(16,18)BF(17,19)BF(20,22)BF(21,23)BF(24,26)BF(25,27)BF(28,30)BF(29,31)\
             BF(32,34)BF(33,35)BF(36,38)BF(37,39)BF(40,42)BF(41,43)BF(44,46)BF(45,47)\
             BF(48,50)BF(49,51)BF(52,54)BF(53,55)BF(56,58)BF(57,59)BF(60,62)BF(61,63)
#define PL4  BF(0,4)BF(1,5)BF(2,6)BF(3,7)BF(8,12)BF(9,13)BF(10,14)BF(11,15)\
             BF(16,20)BF(17,21)BF(18,22)BF(19,23)BF(24,28)BF(25,29)BF(26,30)BF(27,31)\
             BF(32,36)BF(33,37)BF(34,38)BF(35,39)BF(40,44)BF(41,45)BF(42,46)BF(43,47)\
             BF(48,52)BF(49,53)BF(50,54)BF(51,55)BF(56,60)BF(57,61)BF(58,62)BF(59,63)
#define PL8  BF(0,8)BF(1,9)BF(2,10)BF(3,11)BF(4,12)BF(5,13)BF(6,14)BF(7,15)\
             BF(16,24)BF(17,25)BF(18,26)BF(19,27)BF(20,28)BF(21,29)BF(22,30)BF(23,31)\
             BF(32,40)BF(33,41)BF(34,42)BF(35,43)BF(36,44)BF(37,45)BF(38,46)BF(39,47)\
             BF(48,56)BF(49,57)BF(50,58)BF(51,59)BF(52,60)BF(53,61)BF(54,62)BF(55,63)
#define PL16 BF(0,16)BF(1,17)BF(2,18)BF(3,19)BF(4,20)BF(5,21)BF(6,22)BF(7,23)\
             BF(8,24)BF(9,25)BF(10,26)BF(11,27)BF(12,28)BF(13,29)BF(14,30)BF(15,31)\
             BF(32,48)BF(33,49)BF(34,50)BF(35,51)BF(36,52)BF(37,53)BF(38,54)BF(39,55)\
             BF(40,56)BF(41,57)BF(42,58)BF(43,59)BF(44,60)BF(45,61)BF(46,62)BF(47,63)
#define PL32 BF(0,32)BF(1,33)BF(2,34)BF(3,35)BF(4,36)BF(5,37)BF(6,38)BF(7,39)\
             BF(8,40)BF(9,41)BF(10,42)BF(11,43)BF(12,44)BF(13,45)BF(14,46)BF(15,47)\
             BF(16,48)BF(17,49)BF(18,50)BF(19,51)BF(20,52)BF(21,53)BF(22,54)BF(23,55)\
             BF(24,56)BF(25,57)BF(26,58)BF(27,59)BF(28,60)BF(29,61)BF(30,62)BF(31,63)

#define GATE(qq, P) { const int gi = gb + (qq); \
    const float A = RL(gA, gi), B = RL(gB, gi), \
                C = RL(gC, gi), D = RL(gD, gi); P }

// Addressing (fidx into the wave's 4096-slot region; r is a literal):
// pass1: logical i=(r<<6)|l  -> phys = (r<<6) + (l^r)
// pass2: logical i=(l<<6)|r  -> phys = base2 ^ r,  base2 = (l<<6)|l
// Gray store (after pass2): amp i stored at swz(g^-1(i)) = baseG ^ g6inv(r)
#define LDP1(r) a##r = stw[((r) << 6) + (l ^ (r))];
#define STP1(r) stw[((r) << 6) + (l ^ (r))] = a##r;
#define LDP2(r) a##r = stw[base2 ^ (r)];
#define GI6(r)  ((r) ^ ((r) >> 1) ^ ((r) >> 2) ^ ((r) >> 3) ^ ((r) >> 4) ^ ((r) >> 5))
#define STG(r)  stw[baseG ^ GI6(r)] = a##r;

#define R64(M) M(0)M(1)M(2)M(3)M(4)M(5)M(6)M(7)M(8)M(9)M(10)M(11)M(12)M(13)M(14)M(15)\
               M(16)M(17)M(18)M(19)M(20)M(21)M(22)M(23)M(24)M(25)M(26)M(27)M(28)M(29)M(30)M(31)\
               M(32)M(33)M(34)M(35)M(36)M(37)M(38)M(39)M(40)M(41)M(42)M(43)M(44)M(45)M(46)M(47)\
               M(48)M(49)M(50)M(51)M(52)M(53)M(54)M(55)M(56)M(57)M(58)M(59)M(60)M(61)M(62)M(63)
#define R32L(M) M(0)M(1)M(2)M(3)M(4)M(5)M(6)M(7)M(8)M(9)M(10)M(11)M(12)M(13)M(14)M(15)\
                M(16)M(17)M(18)M(19)M(20)M(21)M(22)M(23)M(24)M(25)M(26)M(27)M(28)M(29)M(30)M(31)
#define R32H(M) M(32)M(33)M(34)M(35)M(36)M(37)M(38)M(39)M(40)M(41)M(42)M(43)M(44)M(45)M(46)M(47)\
                M(48)M(49)M(50)M(51)M(52)M(53)M(54)M(55)M(56)M(57)M(58)M(59)M(60)M(61)M(62)M(63)

// init gate-const + embedding helpers (gates 0..11; literal lane reads)
#define GC(q) const float A##q = RL(gA, q), B##q = RL(gB, q), \
                          C##q = RL(gC, q), D##q = RL(gD, q);
#define VQ(q) \
    const float2 v##q##0 = make_float2(fmaf(A##q, c##q, -D##q * s##q), \
                                       fmaf(-B##q, c##q,  C##q * s##q)); \
    const float2 v##q##1 = make_float2(fmaf(C##q, c##q,  B##q * s##q), \
                                       fmaf(-D##q, c##q, -A##q * s##q));
#define SA(g, T, W) a##g = cmul(T, W);
#define ACCP(r) zp = fmaf(a##r.x, a##r.x, fmaf(a##r.y, a##r.y, zp));
#define ACCN(r) zn = fmaf(a##r.x, a##r.x, fmaf(a##r.y, a##r.y, zn));

__global__ __launch_bounds__(TPB) void qsim_kernel(
    const float* __restrict__ x,      // (B, 12)
    const float* __restrict__ w,      // (6, 12, 3)
    const float* __restrict__ hw,     // (2, 1)
    const float* __restrict__ hb,     // (2,)
    float* __restrict__ out)          // (B, 2)
{
    __shared__ float2 st[2 * 4096];   // 64 KB: one 32KB region per wave

    const int tid = threadIdx.x;
    const int wid = tid >> 6;         // wave id (0,1) = element within block
    const int l   = tid & 63;         // lane
    const int e   = blockIdx.x * 2 + wid;
    float2* stw = st + wid * 4096;

    // ---- gate-constant quads into lane slots (lane j holds gate j; 0..60 used)
    float gA, gB, gC, gD;
    {
        const float* wl = w + l * 3;
        float phi = wl[0], th = wl[1], om = wl[2];
        float c, s, ca, sa, cb, sb;
        __sincosf(0.5f * th, &s, &c);
        __sincosf(0.5f * (phi + om), &sa, &ca);
        __sincosf(0.5f * (phi - om), &sb, &cb);
        gA = c * ca; gB = c * sa; gC = s * cb; gD = s * sb;
    }

    // ---- loop-invariant address bases ----
    const int base2 = (l << 6) | l;
    const int gil   = GI6(l);                       // g6^-1(lane)
    const int pl6   = (__popc(l) & 1) ? 0x3F : 0;   // parity(lane) mask
    const int baseG = (gil << 6) | (pl6 ^ gil);

    float2 a0,a1,a2,a3,a4,a5,a6,a7,a8,a9,a10,a11,a12,a13,a14,a15,
           a16,a17,a18,a19,a20,a21,a22,a23,a24,a25,a26,a27,a28,a29,a30,a31,
           a32,a33,a34,a35,a36,a37,a38,a39,a40,a41,a42,a43,a44,a45,a46,a47,
           a48,a49,a50,a51,a52,a53,a54,a55,a56,a57,a58,a59,a60,a61,a62,a63;

    #pragma unroll 1
    for (int k = 0; k < 4; ++k) {     // layers 2..5 (gates 12..59)
        const int gb = (k + 1) * 12;

        // ======== pass 1: state bits 11..6 (qubits 0..5) ========
        if (k == 0) {
            // init = post-layer-1 product state at logical i=(r<<6)|l,
            // amp = prod_q v_q[bit of j], j = g(i):
            //   j bits 11..6 = g6(r); j bit5 = g6(l)bit5 ^ (r&1);
            //   j bits 4..0 = g6(l) bits 4..0.
            const float* xe = x + e * NQ;
            float c0,s0,c1,s1,c2,s2,c3,s3,c4,s4,c5,s5;
            float c6,s6,c7,s7,c8,s8,c9,s9,c10,s10,c11,s11;
            #define EMB(q) __sincosf(0.5f * xe[q], &s##q, &c##q);
            EMB(0) EMB(1) EMB(2) EMB(3) EMB(4)  EMB(5)
            EMB(6) EMB(7) EMB(8) EMB(9) EMB(10) EMB(11)
            #undef EMB
            GC(0) GC(1) GC(2) GC(3) GC(4) GC(5)
            GC(6) GC(7) GC(8) GC(9) GC(10) GC(11)
            VQ(0) VQ(1) VQ(2) VQ(3) VQ(4) VQ(5)
            VQ(6) VQ(7) VQ(8) VQ(9) VQ(10) VQ(11)
            const int gl = l ^ (l >> 1);            // g6(lane)
            // qubits 7..11 from gl bits 4..0
            const float2 w7  = (gl & 16) ? v71  : v70;
            const float2 w8  = (gl & 8)  ? v81  : v80;
            const float2 w9  = (gl & 4)  ? v91  : v90;
            const float2 w10 = (gl & 2)  ? v101 : v100;
            const float2 w11 = (gl & 1)  ? v111 : v110;
            const float2 wcom = cmul(cmul(cmul(w7, w8), cmul(w9, w10)), w11);
            // qubit 6: j bit5 = gl bit5 ^ (r&1)
            const float2 WAc = cmul(wcom, (gl & 32) ? v61 : v60);  // r even
            const float2 WBc = cmul(wcom, (gl & 32) ? v60 : v61);  // r odd
            // TA over qubits 0..2 (j bits 11..9), TB over 3..5 (bits 8..6)
            const float2 h00 = cmul(v00, v10), h01 = cmul(v00, v11);
            const float2 h10 = cmul(v01, v10), h11 = cmul(v01, v11);
            const float2 TA0 = cmul(h00, v20), TA1 = cmul(h00, v21);
            const float2 TA2 = cmul(h01, v20), TA3 = cmul(h01, v21);
            const float2 TA4 = cmul(h10, v20), TA5 = cmul(h10, v21);
            const float2 TA6 = cmul(h11, v20), TA7 = cmul(h11, v21);
            const float2 k00 = cmul(v30, v40), k01 = cmul(v30, v41);
            const float2 k10 = cmul(v31, v40), k11 = cmul(v31, v41);
            const float2 TB0 = cmul(k00, v50), TB1 = cmul(k00, v51);
            const float2 TB2 = cmul(k01, v50), TB3 = cmul(k01, v51);
            const float2 TB4 = cmul(k10, v50), TB5 = cmul(k10, v51);
            const float2 TB6 = cmul(k11, v50), TB7 = cmul(k11, v51);
            const float2 WA0 = cmul(TB0, WAc), WA1 = cmul(TB1, WAc);
            const float2 WA2 = cmul(TB2, WAc), WA3 = cmul(TB3, WAc);
            const float2 WA4 = cmul(TB4, WAc), WA5 = cmul(TB5, WAc);
            const float2 WA6 = cmul(TB6, WAc), WA7 = cmul(TB7, WAc);
            const float2 WB0 = cmul(TB0, WBc), WB1 = cmul(TB1, WBc);
            const float2 WB2 = cmul(TB2, WBc), WB3 = cmul(TB3, WBc);
            const float2 WB4 = cmul(TB4, WBc), WB5 = cmul(TB5, WBc);
            const float2 WB6 = cmul(TB6, WBc), WB7 = cmul(TB7, WBc);
            // amp[r] = TA[g6(r)>>3] * W{r&1}[g6(r)&7]
            SA(0,TA0,WA0)  SA(1,TA0,WB1)  SA(2,TA0,WA3)  SA(3,TA0,WB2)
            SA(4,TA0,WA6)  SA(5,TA0,WB7)  SA(6,TA0,WA5)  SA(7,TA0,WB4)
            SA(8,TA1,WA4)  SA(9,TA1,WB5)  SA(10,TA1,WA7) SA(11,TA1,WB6)
            SA(12,TA1,WA2) SA(13,TA1,WB3) SA(14,TA1,WA1) SA(15,TA1,WB0)
            SA(16,TA3,WA0) SA(17,TA3,WB1) SA(18,TA3,WA3) SA(19,TA3,WB2)
            SA(20,TA3,WA6) SA(21,TA3,WB7) SA(22,TA3,WA5) SA(23,TA3,WB4)
            SA(24,TA2,WA4) SA(25,TA2,WB5) SA(26,TA2,WA7) SA(27,TA2,WB6)
            SA(28,TA2,WA2) SA(29,TA2,WB3) SA(30,TA2,WA1) SA(31,TA2,WB0)
            SA(32,TA6,WA0) SA(33,TA6,WB1) SA(34,TA6,WA3) SA(35,TA6,WB2)
            SA(36,TA6,WA6) SA(37,TA6,WB7) SA(38,TA6,WA5) SA(39,TA6,WB4)
            SA(40,TA7,WA4) SA(41,TA7,WB5) SA(42,TA7,WA7) SA(43,TA7,WB6)
            SA(44,TA7,WA2) SA(45,TA7,WB3) SA(46,TA7,WA1) SA(47,TA7,WB0)
            SA(48,TA5,WA0) SA(49,TA5,WB1) SA(50,TA5,WA3) SA(51,TA5,WB2)
            SA(52,TA5,WA6) SA(53,TA5,WB7) SA(54,TA5,WA5) SA(55,TA5,WB4)
            SA(56,TA4,WA4) SA(57,TA4,WB5) SA(58,TA4,WA7) SA(59,TA4,WB6)
            SA(60,TA4,WA2) SA(61,TA4,WB3) SA(62,TA4,WA1) SA(63,TA4,WB0)
        } else {
            R64(LDP1)
        }
        // reg bit k <-> state bit 6+k <-> qubit 5-k
        GATE(5, PL1) GATE(4, PL2) GATE(3, PL4)
        GATE(2, PL8) GATE(1, PL16) GATE(0, PL32)
        R64(STP1)

        // ======== pass 2: state bits 5..0 (qubits 6..11) ========
        R64(LDP2)
        GATE(11, PL1) GATE(10, PL2) GATE(9, PL4)
        GATE(8, PL8) GATE(7, PL16) GATE(6, PL32)
        R64(STG)                       // Gray perm via g^-1 scatter
    }

    // ---- final layer: gate 60 (qubit 0 = state bit 11 = reg bit 5) ----
    R64(LDP1)
    {
        const float A = RL(gA, 60), B = RL(gB, 60),
                    C = RL(gC, 60), D = RL(gD, 60);
        PL32
    }

    // ---- <Z_0>: + for reg<32 (bit11=0), - for reg>=32 ----
    float zp = 0.0f, zn = 0.0f;
    R32L(ACCP)
    R32H(ACCN)
    float z = zp - zn;
    #pragma unroll
    for (int off = 32; off >= 1; off >>= 1)
        z += __shfl_down(z, off);

    if (l == 0) {
        out[2 * e + 0] = z * hw[0] + hb[0];
        out[2 * e + 1] = z * hw[1] + hb[1];
    }
}

extern "C" void kernel_launch(void* const* d_in, const int* in_sizes, int n_in,
                              void* d_out, int out_size, void* d_ws, size_t ws_size,
                              hipStream_t stream) {
    const float* x  = (const float*)d_in[0];
    const float* w  = (const float*)d_in[1];
    const float* hw = (const float*)d_in[2];
    const float* hb = (const float*)d_in[3];
    float* out = (float*)d_out;
    const int B = in_sizes[0] / NQ;   // 1024
    qsim_kernel<<<B / 2, TPB, 0, stream>>>(x, w, hw, hb, out);
}

// Round 14
// 40.675 us; speedup vs baseline: 1.1151x; 1.1151x over previous
//
#include <hip/hip_runtime.h>

#define NQ 12
#define NSTATE (1 << NQ)   // 4096 amps per batch element
#define NL 6
#define TPB 512            // 8 amp-slots/thread; TWO batch elements per slot

// R12 skeleton (verified) + RZ-RY-RZ decomposition:
//   Rot(phi,th,om) ~ diag(1,e^{i om}) RY(th) diag(1,e^{i phi})  (global phase
//   drops in |.|^2). Gates become 16-FMA real RY butterflies; the two phase
//   diagonals per layer merge into ONE diagonal per layer boundary:
//   M[j] = D_phi(L+1)[j] * D_om(L)[g(j)], applied at pass A after load
//   (the deferred om rides through the Gray perm: bit_p(g(j)) = b_p ^ b_{p+1}).
//   phi(2) is a phi-only diagonal fused into init; om(5)+phi(6) reduce to a
//   single qubit-0 phase fused into the final gate-60 butterfly; om(6) and all
//   layer-6 / om(5) components on qubits 1..11 commute out of <Z_0>.
// Layer 1 folded into init (product state, P1 absorbed via j=g(i) remap).
// LDS: f4 slot = (reA,imA,reB,imB), phys = swz(i) = i ^ ((i>>4)&0xF);
// per-layer Gray perm applied as g^-1 scatter at pass-D store.

typedef float f4 __attribute__((ext_vector_type(4)));

struct A2 { float ar, ai, br, bi; };

__device__ __forceinline__ float RL(float v, int idx) {
    return __int_as_float(__builtin_amdgcn_readlane(__float_as_int(v), idx));
}
__device__ __forceinline__ float2 cmul(float2 u, float2 v) {
    return make_float2(fmaf(u.x, v.x, -u.y * v.y),
                       fmaf(u.x, v.y,  u.y * v.x));
}

// real RY butterfly on both packed elements: 16 FMA
__device__ __forceinline__ void bfy(A2& s0, A2& s1, float c, float s) {
    float n0, n1;
    n0 = fmaf(c, s0.ar, -s * s1.ar); n1 = fmaf(s, s0.ar, c * s1.ar);
    s0.ar = n0; s1.ar = n1;
    n0 = fmaf(c, s0.ai, -s * s1.ai); n1 = fmaf(s, s0.ai, c * s1.ai);
    s0.ai = n0; s1.ai = n1;
    n0 = fmaf(c, s0.br, -s * s1.br); n1 = fmaf(s, s0.br, c * s1.br);
    s0.br = n0; s1.br = n1;
    n0 = fmaf(c, s0.bi, -s * s1.bi); n1 = fmaf(s, s0.bi, c * s1.bi);
    s0.bi = n0; s1.bi = n1;
}

#define BF(i,j) bfy(a##i, a##j, cth, sth)
#define PK0 BF(0,1); BF(2,3); BF(4,5); BF(6,7);
#define PK1 BF(0,2); BF(1,3); BF(4,6); BF(5,7);
#define PK2 BF(0,4); BF(1,5); BF(2,6); BF(3,7);
#define GATE(qq, P) { const float cth = RL(gc, gb + (qq)), \
                                  sth = RL(gs, gb + (qq)); P }

#define LDS4(off) (*(f4*)((char*)st + (off)))
#define LD1(r, ADR) { f4 v = LDS4(ADR(r)); \
    a##r.ar = v.x; a##r.ai = v.y; a##r.br = v.z; a##r.bi = v.w; }
#define ST1(r, ADR) { f4 v = {a##r.ar, a##r.ai, a##r.br, a##r.bi}; \
    LDS4(ADR(r)) = v; }
#define LD8(ADR) { LD1(0,ADR) LD1(1,ADR) LD1(2,ADR) LD1(3,ADR) \
                   LD1(4,ADR) LD1(5,ADR) LD1(6,ADR) LD1(7,ADR) }
#define ST8(ADR) { ST1(0,ADR) ST1(1,ADR) ST1(2,ADR) ST1(3,ADR) \
                   ST1(4,ADR) ST1(5,ADR) ST1(6,ADR) ST1(7,ADR) }

// Byte-address tilings (i = logical index, t = 9-bit thread, r = 3-bit reg):
// A: i=(r<<9)|t   B: i=t[8:6]<<9|r<<6|t[5:0]   C: i=t[8:3]<<6|r<<3|t[2:0]
// D: i=(t<<3)|r   D-scatter: phys = swz(g^-1(i))
#define ADRA(r)  (ptAb + ((r) << 13))
#define ADRB(r)  (ptBb ^ (((r) << 10) ^ (((r) & 3) << 6)))
#define ADRC(r)  (ptCb ^ (((r) << 7) ^ (((r) >> 1) << 4)))
#define ADRD(r)  (ptDb ^ ((r) << 4))
#define GINV3(r) ((r) ^ ((r) >> 1) ^ ((r) >> 2))
#define ADRDS(r) (ptDSb ^ (GINV3(r) << 4))

// ---- init helpers (post-layer-1 product state; verified in R12) ----
#define CM(n, xr, xi, yr, yi) \
    const float n##r = fmaf(xr, yr, -(xi) * (yi)); \
    const float n##i = fmaf(xr, yi,  (xi) * (yr));
#define GCONST(q) const float A##q = RL(gA, q), B##q = RL(gB, q), \
                              C##q = RL(gC, q), D##q = RL(gD, q);
#define VQDEF(q) \
    const float v##q##0r = fmaf(A##q, c##q, -(D##q) * s##q); \
    const float v##q##0i = fmaf(-(B##q), c##q,  (C##q) * s##q); \
    const float v##q##1r = fmaf(C##q, c##q,  (B##q) * s##q); \
    const float v##q##1i = fmaf(-(D##q), c##q, -(A##q) * s##q);
#define WSEL(q, b) \
    const float w##q##r = (tj & (1 << (b))) ? v##q##1r : v##q##0r; \
    const float w##q##i = (tj & (1 << (b))) ? v##q##1i : v##q##0i;
#define SETAMP(g, rp, mm, RE, IM) \
    a##g.RE = fmaf(mm##r, Q##rp##r, -(mm##i) * Q##rp##i); \
    a##g.IM = fmaf(mm##r, Q##rp##i,  (mm##i) * Q##rp##r);

// apply a complex phase W to one packed slot (both elements): 8 FMA
#define APW(g, Wv) { float xr = a##g.ar, xi = a##g.ai; \
    a##g.ar = fmaf(Wv.x, xr, -Wv.y * xi); \
    a##g.ai = fmaf(Wv.x, xi,  Wv.y * xr); \
    xr = a##g.br; xi = a##g.bi; \
    a##g.br = fmaf(Wv.x, xr, -Wv.y * xi); \
    a##g.bi = fmaf(Wv.x, xi,  Wv.y * xr); }

// angle-accumulate terms (pass-A tiling, bit p of j comes from t for p<=8)
#define DTM(p) { float fv = RL(gphi, gb + 11 - (p)); \
                 at += ((t >> (p)) & 1) ? fv : 0.0f; \
                 float wv = RL(gom, gb - 1 - (p)); \
                 at += ((u >> (p)) & 1) ? wv : 0.0f; }
#define DT0(p) { float fv = RL(gphi, 23 - (p)); \
                 a0t += ((t >> (p)) & 1) ? fv : 0.0f; }

// final fused gate: RY(th6_0) * diag(1, e^{i theta}) on qubit 0 (reg bit 2)
#define FBF(g,h) { \
    float s1r = fmaf(cw, a##h.ar, -sw * a##h.ai); \
    float s1i = fmaf(cw, a##h.ai,  sw * a##h.ar); \
    float n0r = fmaf(c6, a##g.ar, -s6 * s1r); \
    float n0i = fmaf(c6, a##g.ai, -s6 * s1i); \
    a##h.ar = fmaf(s6, a##g.ar,  c6 * s1r); \
    a##h.ai = fmaf(s6, a##g.ai,  c6 * s1i); \
    a##g.ar = n0r; a##g.ai = n0i; \
    s1r = fmaf(cw, a##h.br, -sw * a##h.bi); \
    s1i = fmaf(cw, a##h.bi,  sw * a##h.br); \
    n0r = fmaf(c6, a##g.br, -s6 * s1r); \
    n0i = fmaf(c6, a##g.bi, -s6 * s1i); \
    a##h.br = fmaf(s6, a##g.br,  c6 * s1r); \
    a##h.bi = fmaf(s6, a##g.bi,  c6 * s1i); \
    a##g.br = n0r; a##g.bi = n0i; }

__global__ __launch_bounds__(TPB) void qsim_kernel(
    const float* __restrict__ x,      // (B, 12)
    const float* __restrict__ w,      // (6, 12, 3)
    const float* __restrict__ hw,     // (2, 1)
    const float* __restrict__ hb,     // (2,)
    float* __restrict__ out)          // (B, 2)
{
    __shared__ f4 st[NSTATE];         // 64 KB

    const int t    = threadIdx.x;     // 9 bits
    const int lane = t & 63;
    const int e0   = blockIdx.x * 2;

    // ---- prologue: per-lane gate constants (lane g holds gate g, 0..60 used)
    float gA, gB, gC, gD;             // full-Rot quad (init, lanes 0..11)
    float gc, gs;                     // cos/sin(th/2)  (RY butterflies)
    float gcp, gsp, gco, gso;         // cos/sin(phi), cos/sin(om) (F factors)
    float gphi, gom;                  // raw angles (angle accumulation)
    {
        const float* wl = w + lane * 3;
        float phi = wl[0], th = wl[1], om = wl[2];
        float c, s, ca, sa, cb, sb;
        __sincosf(0.5f * th, &s, &c);
        gc = c; gs = s;
        __sincosf(0.5f * (phi + om), &sa, &ca);
        __sincosf(0.5f * (phi - om), &sb, &cb);
        gA = c * ca; gB = c * sa; gC = s * cb; gD = s * sb;
        __sincosf(phi, &gsp, &gcp);
        __sincosf(om,  &gso, &gco);
        gphi = phi; gom = om;
    }

    // ---- loop-invariant BYTE address bases (phys = swz(i) = i^((i>>4)&0xF)) ----
    const int ptAb = (t ^ ((t >> 4) & 0xF)) << 4;
    const int ptBb = (((((t & 0x1C0) << 3) | (t & 0x3F)) ^ ((t >> 4) & 0x3))) << 4;
    const int ptCb = (((((t & 0x1F8) << 3) | (t & 0x7)) ^ (((t >> 3) & 0x3) << 2))) << 4;
    const int ptDb = ((t << 3) ^ ((t >> 1) & 0xF)) << 4;
    int gv = t << 3;
    gv ^= gv >> 1; gv ^= gv >> 2; gv ^= gv >> 4; gv ^= gv >> 8; gv &= 0xFFF;
    const int ptDSb = (gv ^ ((gv >> 4) & 0xF)) << 4;

    const int u = t ^ (t >> 1);       // u_p = t_p ^ t_{p+1}

    A2 a0, a1, a2, a3, a4, a5, a6, a7;

    #pragma unroll 1
    for (int k = 0; k < 4; ++k) {     // layers 2..5 (gates 12..59)
        const int gb = (k + 1) * 12;

        // ---- Pass A: state bits 11..9 (qubits 0..2) ----
        if (k == 0) {
            // init = post-layer-1 product state (P1 absorbed, j = g(i))
            const int tj = t ^ (t >> 1);
            const int t8 = (t >> 8) & 1;
            GCONST(0)  GCONST(1)  GCONST(2)  GCONST(3)
            GCONST(4)  GCONST(5)  GCONST(6)  GCONST(7)
            GCONST(8)  GCONST(9)  GCONST(10) GCONST(11)
            {   // element A
                const float* xe = x + e0 * NQ;
                float c0,s0,c1,s1,c2,s2,c3,s3,c4,s4,c5,s5;
                float c6,s6,c7,s7,c8,s8,c9,s9,c10,s10,c11,s11;
                #define EMB(q) __sincosf(0.5f * xe[q], &s##q, &c##q);
                EMB(0) EMB(1) EMB(2) EMB(3) EMB(4)  EMB(5)
                EMB(6) EMB(7) EMB(8) EMB(9) EMB(10) EMB(11)
                VQDEF(4)  WSEL(4,7)  VQDEF(5)  WSEL(5,6)
                VQDEF(6)  WSEL(6,5)  VQDEF(7)  WSEL(7,4)
                VQDEF(8)  WSEL(8,3)  VQDEF(9)  WSEL(9,2)
                VQDEF(10) WSEL(10,1) VQDEF(11) WSEL(11,0)
                CM(m45, w4r, w4i, w5r, w5i)   CM(m67, w6r, w6i, w7r, w7i)
                CM(m89, w8r, w8i, w9r, w9i)   CM(mAB, w10r, w10i, w11r, w11i)
                CM(mP, m45r, m45i, m67r, m67i) CM(mQ, m89r, m89i, mABr, mABi)
                CM(mL, mPr, mPi, mQr, mQi)
                VQDEF(3)
                const float w3ar = t8 ? v31r : v30r, w3ai = t8 ? v31i : v30i;
                const float w3br = t8 ? v30r : v31r, w3bi = t8 ? v30i : v31i;
                CM(q3a, mLr, mLi, w3ar, w3ai)  CM(q3b, mLr, mLi, w3br, w3bi)
                VQDEF(0) VQDEF(1) VQDEF(2)
                CM(H0, v00r, v00i, v10r, v10i) CM(H1, v00r, v00i, v11r, v11i)
                CM(H2, v01r, v01i, v10r, v10i) CM(H3, v01r, v01i, v11r, v11i)
                CM(Q0, H0r, H0i, v20r, v20i)   CM(Q1, H0r, H0i, v21r, v21i)
                CM(Q2, H1r, H1i, v20r, v20i)   CM(Q3, H1r, H1i, v21r, v21i)
                CM(Q4, H2r, H2i, v20r, v20i)   CM(Q5, H2r, H2i, v21r, v21i)
                CM(Q6, H3r, H3i, v20r, v20i)   CM(Q7, H3r, H3i, v21r, v21i)
                SETAMP(0,0,q3a,ar,ai) SETAMP(1,1,q3b,ar,ai)
                SETAMP(2,3,q3a,ar,ai) SETAMP(3,2,q3b,ar,ai)
                SETAMP(4,6,q3a,ar,ai) SETAMP(5,7,q3b,ar,ai)
                SETAMP(6,5,q3a,ar,ai) SETAMP(7,4,q3b,ar,ai)
            }
            {   // element B
                const float* xe = x + (e0 + 1) * NQ;
                float c0,s0,c1,s1,c2,s2,c3,s3,c4,s4,c5,s5;
                float c6,s6,c7,s7,c8,s8,c9,s9,c10,s10,c11,s11;
                EMB(0) EMB(1) EMB(2) EMB(3) EMB(4)  EMB(5)
                EMB(6) EMB(7) EMB(8) EMB(9) EMB(10) EMB(11)
                #undef EMB
                VQDEF(4)  WSEL(4,7)  VQDEF(5)  WSEL(5,6)
                VQDEF(6)  WSEL(6,5)  VQDEF(7)  WSEL(7,4)
                VQDEF(8)  WSEL(8,3)  VQDEF(9)  WSEL(9,2)
                VQDEF(10) WSEL(10,1) VQDEF(11) WSEL(11,0)
                CM(m45, w4r, w4i, w5r, w5i)   CM(m67, w6r, w6i, w7r, w7i)
                CM(m89, w8r, w8i, w9r, w9i)   CM(mAB, w10r, w10i, w11r, w11i)
                CM(mP, m45r, m45i, m67r, m67i) CM(mQ, m89r, m89i, mABr, mABi)
                CM(mL, mPr, mPi, mQr, mQi)
                VQDEF(3)
                const float w3ar = t8 ? v31r : v30r, w3ai = t8 ? v31i : v30i;
                const float w3br = t8 ? v30r : v31r, w3bi = t8 ? v30i : v31i;
                CM(q3a, mLr, mLi, w3ar, w3ai)  CM(q3b, mLr, mLi, w3br, w3bi)
                VQDEF(0) VQDEF(1) VQDEF(2)
                CM(H0, v00r, v00i, v10r, v10i) CM(H1, v00r, v00i, v11r, v11i)
                CM(H2, v01r, v01i, v10r, v10i) CM(H3, v01r, v01i, v11r, v11i)
                CM(Q0, H0r, H0i, v20r, v20i)   CM(Q1, H0r, H0i, v21r, v21i)
                CM(Q2, H1r, H1i, v20r, v20i)   CM(Q3, H1r, H1i, v21r, v21i)
                CM(Q4, H2r, H2i, v20r, v20i)   CM(Q5, H2r, H2i, v21r, v21i)
                CM(Q6, H3r, H3i, v20r, v20i)   CM(Q7, H3r, H3i, v21r, v21i)
                SETAMP(0,0,q3a,br,bi) SETAMP(1,1,q3b,br,bi)
                SETAMP(2,3,q3a,br,bi) SETAMP(3,2,q3b,br,bi)
                SETAMP(4,6,q3a,br,bi) SETAMP(5,7,q3b,br,bi)
                SETAMP(6,5,q3a,br,bi) SETAMP(7,4,q3b,br,bi)
            }
            // ---- phi(2) diagonal (phi-only), i = (r<<9)|t, lanes 12..23 ----
            {
                float a0t = 0.0f;
                DT0(0) DT0(1) DT0(2) DT0(3) DT0(4)
                DT0(5) DT0(6) DT0(7) DT0(8)
                float2 P0; __sincosf(a0t, &P0.y, &P0.x);
                const float2 Xa = make_float2(RL(gcp,14), RL(gsp,14)); // p=9, q=2
                const float2 Xb = make_float2(RL(gcp,13), RL(gsp,13)); // p=10
                const float2 Xc = make_float2(RL(gcp,12), RL(gsp,12)); // p=11
                const float2 G3 = cmul(Xa, Xb);
                const float2 W1 = cmul(P0, Xa), W2 = cmul(P0, Xb);
                const float2 W3 = cmul(P0, G3), W4 = cmul(P0, Xc);
                const float2 W5 = cmul(W4, Xa), W6 = cmul(W4, Xb);
                const float2 W7 = cmul(W4, G3);
                APW(0, P0) APW(1, W1) APW(2, W2) APW(3, W3)
                APW(4, W4) APW(5, W5) APW(6, W6) APW(7, W7)
            }
        } else {
            LD8(ADRA)
            // ---- merged diagonal M[j] = D_phi(L)[j] * D_om(L-1)[g(j)] ----
            {
                float at = 0.0f;
                DTM(0) DTM(1) DTM(2) DTM(3)
                DTM(4) DTM(5) DTM(6) DTM(7)
                { float f8 = RL(gphi, gb + 3); at += (t & 256) ? f8 : 0.0f; }
                const float w8 = RL(gom, gb - 9);          // p=8, qubit 3
                const float ae = at + ((t & 256) ? w8 : 0.0f);
                const float ao = at + ((t & 256) ? 0.0f : w8);
                float2 Pe, Po;
                __sincosf(ae, &Pe.y, &Pe.x);
                __sincosf(ao, &Po.y, &Po.x);
                const float2 Xp9  = make_float2(RL(gcp, gb+2),  RL(gsp, gb+2));
                const float2 Xw9  = make_float2(RL(gco, gb-10), RL(gso, gb-10));
                const float2 Xp10 = make_float2(RL(gcp, gb+1),  RL(gsp, gb+1));
                const float2 Xw10 = make_float2(RL(gco, gb-11), RL(gso, gb-11));
                const float2 Xp11 = make_float2(RL(gcp, gb+0),  RL(gsp, gb+0));
                const float2 Xw11 = make_float2(RL(gco, gb-12), RL(gso, gb-12));
                const float2 Y11 = cmul(Xp11, Xw11);
                const float2 F1 = cmul(Xp9, Xw9);
                const float2 Bf = cmul(Xw9, Xp10);
                const float2 F2 = cmul(Bf, Xw10);
                const float2 Cf = cmul(Xp9, Xp10);
                const float2 F3 = cmul(Cf, Xw10);
                const float2 F4 = cmul(Xw10, Y11);
                const float2 F5 = cmul(F1, F4);
                const float2 F6 = cmul(Bf, Y11);
                const float2 F7 = cmul(Cf, Y11);
                const float2 W1 = cmul(Po, F1), W2 = cmul(Pe, F2);
                const float2 W3 = cmul(Po, F3), W4 = cmul(Pe, F4);
                const float2 W5 = cmul(Po, F5), W6 = cmul(Pe, F6);
                const float2 W7 = cmul(Po, F7);
                APW(0, Pe) APW(1, W1) APW(2, W2) APW(3, W3)
                APW(4, W4) APW(5, W5) APW(6, W6) APW(7, W7)
            }
        }
        GATE(2, PK0) GATE(1, PK1) GATE(0, PK2)
        ST8(ADRA)
        __syncthreads();

        // ---- Pass B: state bits 8..6 (qubits 3..5) ----
        LD8(ADRB)
        GATE(5, PK0) GATE(4, PK1) GATE(3, PK2)
        ST8(ADRB)
        __syncthreads();

        // ---- Pass C: state bits 5..3 (qubits 6..8) ----
        LD8(ADRC)
        GATE(8, PK0) GATE(7, PK1) GATE(6, PK2)
        ST8(ADRC)
        __syncthreads();

        // ---- Pass D: state bits 2..0 (qubits 9..11) + Gray scatter ----
        LD8(ADRD)
        GATE(11, PK0) GATE(10, PK1) GATE(9, PK2)
        __syncthreads();
        ST8(ADRDS)
        __syncthreads();
    }

    // ---- final: qubit-0 only — diag(1, e^{i(om5_0+phi6_0)}) then RY(th6_0)
    //      (om5/phi6 on qubits 1..11, om6, and the trailing perm commute
    //       out of <Z_0>; bit 11 = pass-A reg bit 2). ----
    LD8(ADRA)
    {
        const float th0 = RL(gom, 48) + RL(gphi, 60);  // om5_0 + phi6_0
        float cw, sw; __sincosf(th0, &sw, &cw);
        const float c6 = RL(gc, 60), s6 = RL(gs, 60);
        FBF(0,4) FBF(1,5) FBF(2,6) FBF(3,7)
    }

    // ---- measurement: <Z_0> = sum(|r<4|^2) - sum(|r>=4|^2) ----
    float za = 0.0f, zb = 0.0f;
    za += a0.ar*a0.ar + a0.ai*a0.ai;  zb += a0.br*a0.br + a0.bi*a0.bi;
    za += a1.ar*a1.ar + a1.ai*a1.ai;  zb += a1.br*a1.br + a1.bi*a1.bi;
    za += a2.ar*a2.ar + a2.ai*a2.ai;  zb += a2.br*a2.br + a2.bi*a2.bi;
    za += a3.ar*a3.ar + a3.ai*a3.ai;  zb += a3.br*a3.br + a3.bi*a3.bi;
    za -= a4.ar*a4.ar + a4.ai*a4.ai;  zb -= a4.br*a4.br + a4.bi*a4.bi;
    za -= a5.ar*a5.ar + a5.ai*a5.ai;  zb -= a5.br*a5.br + a5.bi*a5.bi;
    za -= a6.ar*a6.ar + a6.ai*a6.ai;  zb -= a6.br*a6.br + a6.bi*a6.bi;
    za -= a7.ar*a7.ar + a7.ai*a7.ai;  zb -= a7.br*a7.br + a7.bi*a7.bi;

    #pragma unroll
    for (int off = 32; off >= 1; off >>= 1) {
        za += __shfl_down(za, off);
        zb += __shfl_down(zb, off);
    }

    __syncthreads();
    float* red = (float*)st;
    if (lane == 0) { red[t >> 6] = za; red[8 + (t >> 6)] = zb; }
    __syncthreads();

    if (t == 0) {
        float zta = 0.0f, ztb = 0.0f;
        #pragma unroll
        for (int wv = 0; wv < 8; ++wv) { zta += red[wv]; ztb += red[8 + wv]; }
        out[2 * e0 + 0] = zta * hw[0] + hb[0];
        out[2 * e0 + 1] = zta * hw[1] + hb[1];
        out[2 * e0 + 2] = ztb * hw[0] + hb[0];
        out[2 * e0 + 3] = ztb * hw[1] + hb[1];
    }
}

extern "C" void kernel_launch(void* const* d_in, const int* in_sizes, int n_in,
                              void* d_out, int out_size, void* d_ws, size_t ws_size,
                              hipStream_t stream) {
    const float* x  = (const float*)d_in[0];
    const float* w  = (const float*)d_in[1];
    const float* hw = (const float*)d_in[2];
    const float* hb = (const float*)d_in[3];
    float* out = (float*)d_out;
    const int B = in_sizes[0] / NQ;   // 1024
    qsim_kernel<<<B / 2, TPB, 0, stream>>>(x, w, hw, hb, out);
}

// Round 15
// 39.565 us; speedup vs baseline: 1.1464x; 1.0281x over previous
//
#include <hip/hip_runtime.h>

#define NQ 12
#define NSTATE (1 << NQ)   // 4096 amps per batch element
#define TPB 256            // 16 f4 slots/thread; TWO batch elements per slot

// R12-verified math, restructured to 3 LDS passes per layer (4 qubits/pass).
// f4 slot = (reA,imA,reB,imB) -> ds_*_b128. LDS phys = swz(i) = i^((i>>4)&0xF).
// Layer 1 folded into init (product state; its Gray perm absorbed via j=g(i)).
// Per-layer CNOT Gray perm new[i]=old[g(i)], g(i)=i^(i>>1), applied as a
// g^-1 scatter at pass-C store. Layer 6 amputated to gate 60 only (all other
// layer-6 gates + trailing perm commute out of <Z_0>).
// Gate constants in lane slots, broadcast via v_readlane.

typedef float f4 __attribute__((ext_vector_type(4)));

struct A2 { float ar, ai, br, bi; };

__device__ __forceinline__ float RL(float v, int idx) {
    return __int_as_float(__builtin_amdgcn_readlane(__float_as_int(v), idx));
}

// Rot(phi,theta,omega): u00=(A,-B) u01=(-C,-D) u10=(C,-D) u11=(A,B)
__device__ __forceinline__ void bf2(A2& s0, A2& s1,
                                    float A, float B, float C, float D) {
    float n0r, n0i, n1r, n1i;
    n0r = fmaf(A, s0.ar, fmaf( B, s0.ai, fmaf(-C, s1.ar,  D * s1.ai)));
    n0i = fmaf(A, s0.ai, fmaf(-B, s0.ar, fmaf(-C, s1.ai, -D * s1.ar)));
    n1r = fmaf(C, s0.ar, fmaf( D, s0.ai, fmaf( A, s1.ar, -B * s1.ai)));
    n1i = fmaf(C, s0.ai, fmaf(-D, s0.ar, fmaf( A, s1.ai,  B * s1.ar)));
    s0.ar = n0r; s0.ai = n0i; s1.ar = n1r; s1.ai = n1i;
    n0r = fmaf(A, s0.br, fmaf( B, s0.bi, fmaf(-C, s1.br,  D * s1.bi)));
    n0i = fmaf(A, s0.bi, fmaf(-B, s0.br, fmaf(-C, s1.bi, -D * s1.br)));
    n1r = fmaf(C, s0.br, fmaf( D, s0.bi, fmaf( A, s1.br, -B * s1.bi)));
    n1i = fmaf(C, s0.bi, fmaf(-D, s0.br, fmaf( A, s1.bi,  B * s1.br)));
    s0.br = n0r; s0.bi = n0i; s1.br = n1r; s1.bi = n1i;
}

#define BF(i,j) bf2(a##i, a##j, A, B, C, D)
#define PK0 BF(0,1); BF(2,3); BF(4,5); BF(6,7); \
            BF(8,9); BF(10,11); BF(12,13); BF(14,15);
#define PK1 BF(0,2); BF(1,3); BF(4,6); BF(5,7); \
            BF(8,10); BF(9,11); BF(12,14); BF(13,15);
#define PK2 BF(0,4); BF(1,5); BF(2,6); BF(3,7); \
            BF(8,12); BF(9,13); BF(10,14); BF(11,15);
#define PK3 BF(0,8); BF(1,9); BF(2,10); BF(3,11); \
            BF(4,12); BF(5,13); BF(6,14); BF(7,15);
#define GATE(qq, P) { const int gi = gb + (qq); \
    const float A = RL(gA, gi), B = RL(gB, gi), \
                C = RL(gC, gi), D = RL(gD, gi); P }

#define LDS4(off) (*(f4*)((char*)st + (off)))
#define LD1(r, ADR) { f4 v = LDS4(ADR(r)); \
    a##r.ar = v.x; a##r.ai = v.y; a##r.br = v.z; a##r.bi = v.w; }
#define ST1(r, ADR) { f4 v = {a##r.ar, a##r.ai, a##r.br, a##r.bi}; \
    LDS4(ADR(r)) = v; }
#define LD16(ADR) { LD1(0,ADR) LD1(1,ADR) LD1(2,ADR) LD1(3,ADR) \
                    LD1(4,ADR) LD1(5,ADR) LD1(6,ADR) LD1(7,ADR) \
                    LD1(8,ADR) LD1(9,ADR) LD1(10,ADR) LD1(11,ADR) \
                    LD1(12,ADR) LD1(13,ADR) LD1(14,ADR) LD1(15,ADR) }
#define ST16(ADR) { ST1(0,ADR) ST1(1,ADR) ST1(2,ADR) ST1(3,ADR) \
                    ST1(4,ADR) ST1(5,ADR) ST1(6,ADR) ST1(7,ADR) \
                    ST1(8,ADR) ST1(9,ADR) ST1(10,ADR) ST1(11,ADR) \
                    ST1(12,ADR) ST1(13,ADR) ST1(14,ADR) ST1(15,ADR) }

// Byte-address tilings (t = 8-bit thread, r = 4-bit reg, slot byte = idx<<4):
// A: i=(r<<8)|t  -> phys = (r<<8)+(t^(t>>4))          (offset-immediate)
// B: i=t[7:4]<<8|r<<4|t[3:0] -> phys = ptB ^ (r<<4) ^ r
// C: i=(t<<4)|r  -> phys = (t<<4)+((t&0xF)^r)
// C-scatter: store i at swz(g^-1(i)) = ptCS ^ ginv4(r)
#define ADRA(r)   (ptAb + ((r) << 12))
#define ADRB(r)   (ptBb ^ (((r) << 8) ^ ((r) << 4)))
#define ADRC(r)   (ptCb ^ ((r) << 4))
#define GINV4(r)  ((r) ^ ((r) >> 1) ^ ((r) >> 2) ^ ((r) >> 3))
#define ADRCS(r)  (ptCSb ^ (GINV4(r) << 4))

// ---- init helpers (post-layer-1 product state; R12-verified algebra) ----
#define CM(n, xr, xi, yr, yi) \
    const float n##r = fmaf(xr, yr, -(xi) * (yi)); \
    const float n##i = fmaf(xr, yi,  (xi) * (yr));
#define GCONST(q) const float A##q = RL(gA, q), B##q = RL(gB, q), \
                              C##q = RL(gC, q), D##q = RL(gD, q);
// v_q = Rot_q * (cos, -i sin)
#define VQDEF(q) \
    const float v##q##0r = fmaf(A##q, c##q, -(D##q) * s##q); \
    const float v##q##0i = fmaf(-(B##q), c##q,  (C##q) * s##q); \
    const float v##q##1r = fmaf(C##q, c##q,  (B##q) * s##q); \
    const float v##q##1i = fmaf(-(D##q), c##q, -(A##q) * s##q);
#define WSEL(q, b) \
    const float w##q##r = (tj & (1 << (b))) ? v##q##1r : v##q##0r; \
    const float w##q##i = (tj & (1 << (b))) ? v##q##1i : v##q##0i;
#define SETAMP(g, rp, mm, RE, IM) \
    a##g.RE = fmaf(mm##r, Q##rp##r, -(mm##i) * Q##rp##i); \
    a##g.IM = fmaf(mm##r, Q##rp##i,  (mm##i) * Q##rp##r);

__global__ __launch_bounds__(TPB) void qsim_kernel(
    const float* __restrict__ x,      // (B, 12)
    const float* __restrict__ w,      // (6, 12, 3)
    const float* __restrict__ hw,     // (2, 1)
    const float* __restrict__ hb,     // (2,)
    float* __restrict__ out)          // (B, 2)
{
    __shared__ f4 st[NSTATE];         // 64 KB

    const int t    = threadIdx.x;     // 8 bits
    const int lane = t & 63;
    const int e0   = blockIdx.x * 2;

    // ---- prologue: gate-constant quads into lane slots (gates 0..60 used) ----
    float gA, gB, gC, gD;
    {
        const float* wl = w + lane * 3;
        float phi = wl[0], th = wl[1], om = wl[2];
        float c, s, ca, sa, cb, sb;
        __sincosf(0.5f * th, &s, &c);
        __sincosf(0.5f * (phi + om), &sa, &ca);
        __sincosf(0.5f * (phi - om), &sb, &cb);
        gA = c * ca; gB = c * sa; gC = s * cb; gD = s * sb;
    }

    // ---- loop-invariant BYTE address bases ----
    const int ptAb  = (t ^ (t >> 4)) << 4;                    // swz(t), t<256
    const int ptBb  = ((((t & 0xF0) << 4) | (t & 0x0F))) << 4;
    const int ptCb  = (((t << 4) ^ (t & 0x0F))) << 4;
    int gv = t << 4;                  // g^-1 = suffix parity (GF(2)-linear)
    gv ^= gv >> 1; gv ^= gv >> 2; gv ^= gv >> 4; gv ^= gv >> 8; gv &= 0xFFF;
    const int ptCSb = (gv ^ ((gv >> 4) & 0xF)) << 4;

    A2 a0, a1, a2, a3, a4, a5, a6, a7,
       a8, a9, a10, a11, a12, a13, a14, a15;

    #pragma unroll 1
    for (int k = 0; k < 4; ++k) {     // layers 2..5 (gates 12..59)
        const int gb = (k + 1) * 12;

        // ---- Pass A: state bits 11..8 (qubits 0..3) ----
        if (k == 0) {
            // init = post-layer-1 product state at i=(r<<8)|t, j = g(i):
            //   j11..9 = g4(r)>>1, j8 = r0^r1, j7 = t7^r0, j6..0 = tj bits 6..0
            const int tj = t ^ (t >> 1);
            const int t7 = (t >> 7) & 1;
            GCONST(0)  GCONST(1)  GCONST(2)  GCONST(3)
            GCONST(4)  GCONST(5)  GCONST(6)  GCONST(7)
            GCONST(8)  GCONST(9)  GCONST(10) GCONST(11)
            {   // element A
                const float* xe = x + e0 * NQ;
                float c0,s0,c1,s1,c2,s2,c3,s3,c4,s4,c5,s5;
                float c6,s6,c7,s7,c8,s8,c9,s9,c10,s10,c11,s11;
                #define EMB(q) __sincosf(0.5f * xe[q], &s##q, &c##q);
                EMB(0) EMB(1) EMB(2) EMB(3) EMB(4)  EMB(5)
                EMB(6) EMB(7) EMB(8) EMB(9) EMB(10) EMB(11)
                // qubits 5..11 from tj bits 6..0
                VQDEF(5)  WSEL(5,6)  VQDEF(6)  WSEL(6,5)
                VQDEF(7)  WSEL(7,4)  VQDEF(8)  WSEL(8,3)
                VQDEF(9)  WSEL(9,2)  VQDEF(10) WSEL(10,1)
                VQDEF(11) WSEL(11,0)
                CM(m56, w5r, w5i, w6r, w6i)   CM(m78, w7r, w7i, w8r, w8i)
                CM(m9A, w9r, w9i, w10r, w10i)
                CM(mP, m56r, m56i, m78r, m78i) CM(mQ, m9Ar, m9Ai, w11r, w11i)
                CM(mL, mPr, mPi, mQr, mQi)     // product over qubits 5..11
                // qubit 4: j7 = t7 ^ r0
                VQDEF(4)
                const float w4ar = t7 ? v41r : v40r, w4ai = t7 ? v41i : v40i;
                const float w4br = t7 ? v40r : v41r, w4bi = t7 ? v40i : v41i;
                CM(Pa, mLr, mLi, w4ar, w4ai)   CM(Pb, mLr, mLi, w4br, w4bi)
                // qubit 3: j8 = r0^r1
                VQDEF(3)
                CM(T00, Par, Pai, v30r, v30i)  CM(T01, Par, Pai, v31r, v31i)
                CM(T10, Pbr, Pbi, v31r, v31i)  CM(T11, Pbr, Pbi, v30r, v30i)
                // qubits 0..2: Q[z], z = g4(r)>>1 (bit2=q0, bit1=q1, bit0=q2)
                VQDEF(0) VQDEF(1) VQDEF(2)
                CM(H0, v00r, v00i, v10r, v10i) CM(H1, v00r, v00i, v11r, v11i)
                CM(H2, v01r, v01i, v10r, v10i) CM(H3, v01r, v01i, v11r, v11i)
                CM(Q0, H0r, H0i, v20r, v20i)   CM(Q1, H0r, H0i, v21r, v21i)
                CM(Q2, H1r, H1i, v20r, v20i)   CM(Q3, H1r, H1i, v21r, v21i)
                CM(Q4, H2r, H2i, v20r, v20i)   CM(Q5, H2r, H2i, v21r, v21i)
                CM(Q6, H3r, H3i, v20r, v20i)   CM(Q7, H3r, H3i, v21r, v21i)
                SETAMP(0,0,T00,ar,ai)  SETAMP(1,0,T10,ar,ai)
                SETAMP(2,1,T01,ar,ai)  SETAMP(3,1,T11,ar,ai)
                SETAMP(4,3,T00,ar,ai)  SETAMP(5,3,T10,ar,ai)
                SETAMP(6,2,T01,ar,ai)  SETAMP(7,2,T11,ar,ai)
                SETAMP(8,6,T00,ar,ai)  SETAMP(9,6,T10,ar,ai)
                SETAMP(10,7,T01,ar,ai) SETAMP(11,7,T11,ar,ai)
                SETAMP(12,5,T00,ar,ai) SETAMP(13,5,T10,ar,ai)
                SETAMP(14,4,T01,ar,ai) SETAMP(15,4,T11,ar,ai)
            }
            {   // element B
                const float* xe = x + (e0 + 1) * NQ;
                float c0,s0,c1,s1,c2,s2,c3,s3,c4,s4,c5,s5;
                float c6,s6,c7,s7,c8,s8,c9,s9,c10,s10,c11,s11;
                EMB(0) EMB(1) EMB(2) EMB(3) EMB(4)  EMB(5)
                EMB(6) EMB(7) EMB(8) EMB(9) EMB(10) EMB(11)
                #undef EMB
                VQDEF(5)  WSEL(5,6)  VQDEF(6)  WSEL(6,5)
                VQDEF(7)  WSEL(7,4)  VQDEF(8)  WSEL(8,3)
                VQDEF(9)  WSEL(9,2)  VQDEF(10) WSEL(10,1)
                VQDEF(11) WSEL(11,0)
                CM(m56, w5r, w5i, w6r, w6i)   CM(m78, w7r, w7i, w8r, w8i)
                CM(m9A, w9r, w9i, w10r, w10i)
                CM(mP, m56r, m56i, m78r, m78i) CM(mQ, m9Ar, m9Ai, w11r, w11i)
                CM(mL, mPr, mPi, mQr, mQi)
                VQDEF(4)
                const float w4ar = t7 ? v41r : v40r, w4ai = t7 ? v41i : v40i;
                const float w4br = t7 ? v40r : v41r, w4bi = t7 ? v40i : v41i;
                CM(Pa, mLr, mLi, w4ar, w4ai)   CM(Pb, mLr, mLi, w4br, w4bi)
                VQDEF(3)
                CM(T00, Par, Pai, v30r, v30i)  CM(T01, Par, Pai, v31r, v31i)
                CM(T10, Pbr, Pbi, v31r, v31i)  CM(T11, Pbr, Pbi, v30r, v30i)
                VQDEF(0) VQDEF(1) VQDEF(2)
                CM(H0, v00r, v00i, v10r, v10i) CM(H1, v00r, v00i, v11r, v11i)
                CM(H2, v01r, v01i, v10r, v10i) CM(H3, v01r, v01i, v11r, v11i)
                CM(Q0, H0r, H0i, v20r, v20i)   CM(Q1, H0r, H0i, v21r, v21i)
                CM(Q2, H1r, H1i, v20r, v20i)   CM(Q3, H1r, H1i, v21r, v21i)
                CM(Q4, H2r, H2i, v20r, v20i)   CM(Q5, H2r, H2i, v21r, v21i)
                CM(Q6, H3r, H3i, v20r, v20i)   CM(Q7, H3r, H3i, v21r, v21i)
                SETAMP(0,0,T00,br,bi)  SETAMP(1,0,T10,br,bi)
                SETAMP(2,1,T01,br,bi)  SETAMP(3,1,T11,br,bi)
                SETAMP(4,3,T00,br,bi)  SETAMP(5,3,T10,br,bi)
                SETAMP(6,2,T01,br,bi)  SETAMP(7,2,T11,br,bi)
                SETAMP(8,6,T00,br,bi)  SETAMP(9,6,T10,br,bi)
                SETAMP(10,7,T01,br,bi) SETAMP(11,7,T11,br,bi)
                SETAMP(12,5,T00,br,bi) SETAMP(13,5,T10,br,bi)
                SETAMP(14,4,T01,br,bi) SETAMP(15,4,T11,br,bi)
            }
        } else {
            LD16(ADRA)
        }
        // reg bit k <-> state bit 8+k <-> qubit 3-k
        GATE(3, PK0) GATE(2, PK1) GATE(1, PK2) GATE(0, PK3)
        ST16(ADRA)
        __syncthreads();

        // ---- Pass B: state bits 7..4 (qubits 4..7) ----
        LD16(ADRB)
        GATE(7, PK0) GATE(6, PK1) GATE(5, PK2) GATE(4, PK3)
        ST16(ADRB)
        __syncthreads();

        // ---- Pass C: state bits 3..0 (qubits 8..11) + Gray scatter ----
        LD16(ADRC)
        GATE(11, PK0) GATE(10, PK1) GATE(9, PK2) GATE(8, PK3)
        __syncthreads();              // all pass-C reads done before scatter
        ST16(ADRCS)                   // Gray perm via g^-1 scatter
        __syncthreads();
    }

    // ---- final layer (w[5]): only gate 60 (qubit 0 = state bit 11 = reg
    //      bit 3) survives inside <Z_0>; the rest commutes out. ----
    LD16(ADRA)
    {
        const float A = RL(gA, 60), B = RL(gB, 60),
                    C = RL(gC, 60), D = RL(gD, 60);
        bf2(a0, a8,  A, B, C, D); bf2(a1, a9,  A, B, C, D);
        bf2(a2, a10, A, B, C, D); bf2(a3, a11, A, B, C, D);
        bf2(a4, a12, A, B, C, D); bf2(a5, a13, A, B, C, D);
        bf2(a6, a14, A, B, C, D); bf2(a7, a15, A, B, C, D);
    }

    // ---- <Z_0> = sum(|r<8|^2) - sum(|r>=8|^2) ----
    float za = 0.0f, zb = 0.0f;
    za += a0.ar*a0.ar + a0.ai*a0.ai;    zb += a0.br*a0.br + a0.bi*a0.bi;
    za += a1.ar*a1.ar + a1.ai*a1.ai;    zb += a1.br*a1.br + a1.bi*a1.bi;
    za += a2.ar*a2.ar + a2.ai*a2.ai;    zb += a2.br*a2.br + a2.bi*a2.bi;
    za += a3.ar*a3.ar + a3.ai*a3.ai;    zb += a3.br*a3.br + a3.bi*a3.bi;
    za += a4.ar*a4.ar + a4.ai*a4.ai;    zb += a4.br*a4.br + a4.bi*a4.bi;
    za += a5.ar*a5.ar + a5.ai*a5.ai;    zb += a5.br*a5.br + a5.bi*a5.bi;
    za += a6.ar*a6.ar + a6.ai*a6.ai;    zb += a6.br*a6.br + a6.bi*a6.bi;
    za += a7.ar*a7.ar + a7.ai*a7.ai;    zb += a7.br*a7.br + a7.bi*a7.bi;
    za -= a8.ar*a8.ar + a8.ai*a8.ai;    zb -= a8.br*a8.br + a8.bi*a8.bi;
    za -= a9.ar*a9.ar + a9.ai*a9.ai;    zb -= a9.br*a9.br + a9.bi*a9.bi;
    za -= a10.ar*a10.ar + a10.ai*a10.ai; zb -= a10.br*a10.br + a10.bi*a10.bi;
    za -= a11.ar*a11.ar + a11.ai*a11.ai; zb -= a11.br*a11.br + a11.bi*a11.bi;
    za -= a12.ar*a12.ar + a12.ai*a12.ai; zb -= a12.br*a12.br + a12.bi*a12.bi;
    za -= a13.ar*a13.ar + a13.ai*a13.ai; zb -= a13.br*a13.br + a13.bi*a13.bi;
    za -= a14.ar*a14.ar + a14.ai*a14.ai; zb -= a14.br*a14.br + a14.bi*a14.bi;
    za -= a15.ar*a15.ar + a15.ai*a15.ai; zb -= a15.br*a15.br + a15.bi*a15.bi;

    #pragma unroll
    for (int off = 32; off >= 1; off >>= 1) {
        za += __shfl_down(za, off);
        zb += __shfl_down(zb, off);
    }

    __syncthreads();                  // all final-pass reads done before reuse
    float* red = (float*)st;
    if (lane == 0) { red[t >> 6] = za; red[4 + (t >> 6)] = zb; }
    __syncthreads();

    if (t == 0) {
        float zta = red[0] + red[1] + red[2] + red[3];
        float ztb = red[4] + red[5] + red[6] + red[7];
        out[2 * e0 + 0] = zta * hw[0] + hb[0];
        out[2 * e0 + 1] = zta * hw[1] + hb[1];
        out[2 * e0 + 2] = ztb * hw[0] + hb[0];
        out[2 * e0 + 3] = ztb * hw[1] + hb[1];
    }
}

extern "C" void kernel_launch(void* const* d_in, const int* in_sizes, int n_in,
                              void* d_out, int out_size, void* d_ws, size_t ws_size,
                              hipStream_t stream) {
    const float* x  = (const float*)d_in[0];
    const float* w  = (const float*)d_in[1];
    const float* hw = (const float*)d_in[2];
    const float* hb = (const float*)d_in[3];
    float* out = (float*)d_out;
    const int B = in_sizes[0] / NQ;   // 1024
    qsim_kernel<<<B / 2, TPB, 0, stream>>>(x, w, hw, hb, out);
}